// Round 8
// baseline (214.143 us; speedup 1.0000x reference)
//
#include <hip/hip_runtime.h>
#include <hip/hip_bf16.h>
#include <cstdint>
#include <cstddef>

#define HID 512
#define T_SZ 4096

typedef __bf16 bf16x8 __attribute__((ext_vector_type(8)));
typedef float f32x4 __attribute__((ext_vector_type(4)));

__device__ __forceinline__ unsigned short f2bf_rne(float f) {
    unsigned int u = __float_as_uint(f);
    unsigned int r = (u + 0x7FFFu + ((u >> 16) & 1u)) >> 16;
    return (unsigned short)r;
}

__device__ __forceinline__ bf16x8 pack8(float4 x0, float4 x1) {
    bf16x8 r;
    r[0] = (__bf16)x0.x; r[1] = (__bf16)x0.y; r[2] = (__bf16)x0.z; r[3] = (__bf16)x0.w;
    r[4] = (__bf16)x1.x; r[5] = (__bf16)x1.y; r[6] = (__bf16)x1.z; r[7] = (__bf16)x1.w;
    return r;
}

__device__ __forceinline__ float fast_tanh(float x) {
    float e = __expf(2.0f * x);
    return 1.0f - 2.0f / (e + 1.0f);
}

// ---------------- kernel 1: s[b][n] = dot(dec[b,:], Ws[n,:]) ----------------
__global__ void k_s(const float* __restrict__ dec, const float* __restrict__ Ws,
                    float* __restrict__ s) {
    int idx = blockIdx.x * 256 + threadIdx.x;   // 16384 = 32*512
    int b = idx >> 9, n = idx & 511;
    const float4* dp = reinterpret_cast<const float4*>(dec + (size_t)b * HID);
    const float4* wp = reinterpret_cast<const float4*>(Ws + (size_t)n * HID);
    float acc = 0.f;
#pragma unroll 8
    for (int i = 0; i < HID / 4; ++i) {
        float4 d = dp[i], w = wp[i];
        acc += d.x * w.x + d.y * w.y + d.z * w.z + d.w * w.w;
    }
    s[idx] = acc;
}

// ------------- kernel 2: pack W_h -> bf16 fragments (kk-major) --------------
// Chunk index = kk*2048 + n4*64 + (g*16 + c); chunk (uint4) holds
// W[n4*16 + c][kk*32 + g*8 + j], j=0..7 as bf16.
__global__ void k_pack(const float* __restrict__ Wh, uint4* __restrict__ Wb) {
    int idx = blockIdx.x * 256 + threadIdx.x;   // 32768, 8 elems each
    int n = idx >> 6;
    int k0 = (idx & 63) * 8;
    const float4* p = reinterpret_cast<const float4*>(Wh + (size_t)n * HID + k0);
    float4 x0 = p[0], x1 = p[1];
    uint4 w;
    w.x = f2bf_rne(x0.x) | ((unsigned)f2bf_rne(x0.y) << 16);
    w.y = f2bf_rne(x0.z) | ((unsigned)f2bf_rne(x0.w) << 16);
    w.z = f2bf_rne(x1.x) | ((unsigned)f2bf_rne(x1.y) << 16);
    w.w = f2bf_rne(x1.z) | ((unsigned)f2bf_rne(x1.w) << 16);
    int n4 = n >> 4, c = n & 15, kk = k0 >> 5, g = (k0 >> 3) & 3;
    Wb[(size_t)kk * 2048 + n4 * 64 + g * 16 + c] = w;
}

// ------------- kernel 3: fused h = enc@Wh^T ; e_part = sum tanh(h+s).v ------
// BM=64, BN=256 (h-half), 512 threads = 8 waves (2m x 4n), wave = 32x64 out.
// Whole A tile (64KB) staged once: LDS dest LINEAR in tid (conflict-free),
// global src is the inverse map (128B fully-consumed row segments).
// K-loop: ZERO barriers; A frags dbuf'd from LDS, B via depth-2 reg ring
// from L2-resident Wb (consume slot THEN refill).  ~115 regs -> 4 waves/SIMD.
__global__ void __launch_bounds__(512, 4) k_gemm_e(
    const float* __restrict__ enc, const uint4* __restrict__ Wb,
    const float* __restrict__ s, const float* __restrict__ v,
    float* __restrict__ part_e) {
    __shared__ __align__(16) unsigned char As[65536];  // [kk][chunk] 16B linear
    __shared__ float red[2][4][32];

    const int tid = threadIdx.x;
    // bijective XCD swizzle: 4096 = 8 XCD x 512; h-pairs adjacent -> same XCD.
    const int p = blockIdx.x;
    const int logical = (p & 7) * 512 + (p >> 3);
    const int h = logical & 1;
    const int m = logical >> 1;                 // 0..2047
    const size_t row0 = (size_t)m * 64;
    const int b = (int)(row0 >> 12);

    const int lane = tid & 63, wid = tid >> 6;
    const int c = lane & 15, g4 = lane >> 4;
    const int wm = wid >> 2, wn = wid & 3;      // 2 x 4 wave grid

    // epilogue constants
    float sv_s[4], sv_v[4];
#pragma unroll
    for (int ni = 0; ni < 4; ++ni) {
        int n = (h * 16 + wn * 4 + ni) * 16 + c;
        sv_s[ni] = s[b * HID + n];
        sv_v[ni] = v[n];
    }

    // ---- stage A tile: thread handles chunks G = i*512+tid, LDS = G*16 ----
    {
        const float* base = enc + row0 * HID;
#pragma unroll
        for (int i = 0; i < 8; ++i) {
            int G = i * 512 + tid;
            int kk = G >> 8, cin = G & 255;
            int mi = cin >> 6, gg = (cin >> 4) & 3, cc = cin & 15;
            const float* src = base + (size_t)(mi * 16 + cc) * HID + kk * 32 + gg * 8;
            float4 x0 = *reinterpret_cast<const float4*>(src);
            float4 x1 = *reinterpret_cast<const float4*>(src + 4);
            *reinterpret_cast<bf16x8*>(&As[G * 16]) = pack8(x0, x1);
        }
    }
    __syncthreads();   // the ONLY staging barrier

    // B fragment stream: chunk = kk*2048 + n4*64 + lane, n4 = h*16+wn*4+ni
    const uint4* Bg = Wb + (size_t)(h * 16 + wn * 4) * 64 + lane;

    uint4 bR[2][4];    // depth-2 ring
#pragma unroll
    for (int d = 0; d < 2; ++d)
#pragma unroll
        for (int ni = 0; ni < 4; ++ni)
            bR[d][ni] = Bg[(size_t)d * 2048 + ni * 64];

    bf16x8 af[2][2];
#pragma unroll
    for (int mi = 0; mi < 2; ++mi)
        af[0][mi] = *reinterpret_cast<const bf16x8*>(&As[((wm * 2 + mi) * 64 + lane) * 16]);

    f32x4 acc[2][4] = {};   // [mi][ni]

#pragma unroll
    for (int kk = 0; kk < 16; ++kk) {
        // prefetch A(kk+1) fragments from LDS (tile static, no barrier)
        if (kk < 15) {
#pragma unroll
            for (int mi = 0; mi < 2; ++mi)
                af[(kk + 1) & 1][mi] = *reinterpret_cast<const bf16x8*>(
                    &As[(kk + 1) * 4096 + ((wm * 2 + mi) * 64 + lane) * 16]);
        }
        // consume B slot kk&1
#pragma unroll
        for (int mi = 0; mi < 2; ++mi)
#pragma unroll
            for (int ni = 0; ni < 4; ++ni)
                acc[mi][ni] = __builtin_amdgcn_mfma_f32_16x16x32_bf16(
                    af[kk & 1][mi], *reinterpret_cast<bf16x8*>(&bR[kk & 1][ni]),
                    acc[mi][ni], 0, 0, 0);
        // refill slot kk&1 with B(kk+2) — AFTER consumption in program order
        if (kk + 2 <= 15) {
#pragma unroll
            for (int ni = 0; ni < 4; ++ni)
                bR[kk & 1][ni] = Bg[(size_t)(kk + 2) * 2048 + ni * 64];
        }
    }

    // ---- epilogue: e_part[row] += tanh(h + s[n]) * v[n] over 64 n's --------
    float e_part[2][4] = {};   // [mi][r]
#pragma unroll
    for (int ni = 0; ni < 4; ++ni) {
        float sn = sv_s[ni], vn = sv_v[ni];
#pragma unroll
        for (int mi = 0; mi < 2; ++mi)
#pragma unroll
            for (int r = 0; r < 4; ++r)
                e_part[mi][r] += fast_tanh(acc[mi][ni][r] + sn) * vn;
    }
    // reduce across the 16 n-residue lanes (bits 0..3)
#pragma unroll
    for (int mm = 1; mm <= 8; mm <<= 1)
#pragma unroll
        for (int mi = 0; mi < 2; ++mi)
#pragma unroll
            for (int r = 0; r < 4; ++r)
                e_part[mi][r] += __shfl_xor(e_part[mi][r], mm);

    if (c == 0) {
#pragma unroll
        for (int mi = 0; mi < 2; ++mi)
#pragma unroll
            for (int r = 0; r < 4; ++r)
                red[wm][wn][mi * 16 + g4 * 4 + r] = e_part[mi][r];
    }
    __syncthreads();
    if (tid < 64) {
        int wm2 = tid >> 5, rl = tid & 31;
        part_e[(size_t)h * 131072 + row0 + tid] =
            red[wm2][0][rl] + red[wm2][1][rl] + red[wm2][2][rl] + red[wm2][3][rl];
    }
}

// ---------------- kernel 4: e = part0+part1; masked softmax -> a ------------
__global__ void k_softmax(const float* __restrict__ part_e, float* __restrict__ a,
                          const int* __restrict__ mask) {
    int b = blockIdx.x, tid = threadIdx.x;     // 1024 threads
    int lane = tid & 63, wid = tid >> 6;       // 16 waves
    __shared__ float red[16];
    float vals[4]; int ms[4];
    float mx = -1e30f;
#pragma unroll
    for (int j = 0; j < 4; ++j) {
        size_t t = (size_t)b * T_SZ + tid + j * 1024;
        vals[j] = part_e[t] + part_e[131072 + t];
        ms[j] = mask[t];
        if (ms[j]) mx = fmaxf(mx, vals[j]);
    }
#pragma unroll
    for (int m = 32; m >= 1; m >>= 1) mx = fmaxf(mx, __shfl_xor(mx, m));
    if (lane == 0) red[wid] = mx;
    __syncthreads();
    if (tid == 0) {
        float m2 = red[0];
        for (int i = 1; i < 16; ++i) m2 = fmaxf(m2, red[i]);
        red[0] = m2;
    }
    __syncthreads();
    mx = red[0];
    __syncthreads();
    float pv[4]; float sum = 0.f;
#pragma unroll
    for (int j = 0; j < 4; ++j) { pv[j] = ms[j] ? __expf(vals[j] - mx) : 0.f; sum += pv[j]; }
#pragma unroll
    for (int m = 32; m >= 1; m >>= 1) sum += __shfl_xor(sum, m);
    if (lane == 0) red[wid] = sum;
    __syncthreads();
    if (tid == 0) {
        float s2 = 0.f;
        for (int i = 0; i < 16; ++i) s2 += red[i];
        red[0] = s2;
    }
    __syncthreads();
    float inv = 1.f / red[0];
#pragma unroll
    for (int j = 0; j < 4; ++j)
        a[(size_t)b * T_SZ + tid + j * 1024] = pv[j] * inv;
}

// ---------------- kernel 5: ctx partials over T-chunks ----------------------
__global__ void k_ctx(const float* __restrict__ enc, const float* __restrict__ a,
                      float2* __restrict__ part) {
    int ts = blockIdx.x, b = blockIdx.y, tid = threadIdx.x;   // 32 x 32, 256 thr
    size_t rbase = (size_t)b * T_SZ + (size_t)ts * 128;
    const float2* ep = reinterpret_cast<const float2*>(enc + rbase * HID) + tid;
    const float* ap = a + rbase;
    float ax = 0.f, ay = 0.f, bx = 0.f, by = 0.f;
#pragma unroll 2
    for (int t = 0; t < 128; t += 2) {
        float a0 = ap[t], a1 = ap[t + 1];
        float2 e0 = ep[(size_t)t * 256], e1 = ep[(size_t)(t + 1) * 256];
        ax += a0 * e0.x; ay += a0 * e0.y;
        bx += a1 * e1.x; by += a1 * e1.y;
    }
    float2 r; r.x = ax + bx; r.y = ay + by;
    part[(size_t)(b * 32 + ts) * 256 + tid] = r;
}

// ---------------- kernel 6: reduce partials -> ctx --------------------------
__global__ void k_ctxred(const float* __restrict__ part, float* __restrict__ ctx) {
    int idx = blockIdx.x * 256 + threadIdx.x;   // 16384
    int b = idx >> 9, h = idx & 511;
    float sum = 0.f;
#pragma unroll
    for (int ts = 0; ts < 32; ++ts) sum += part[(size_t)(b * 32 + ts) * 512 + h];
    ctx[idx] = sum;
}

extern "C" void kernel_launch(void* const* d_in, const int* in_sizes, int n_in,
                              void* d_out, int out_size, void* d_ws, size_t ws_size,
                              hipStream_t stream) {
    const float* enc  = (const float*)d_in[0];   // [32,4096,512]
    const int*   mask = (const int*)d_in[1];     // [32,4096]
    const float* dec  = (const float*)d_in[2];   // [32,512]
    const float* Wh   = (const float*)d_in[3];   // [512,512]
    const float* Ws   = (const float*)d_in[4];   // [512,512]
    const float* v    = (const float*)d_in[5];   // [512]

    float* out = (float*)d_out;
    float* ctx = out;                // 16384 floats
    float* a   = out + 16384;        // 131072 floats

    // ws layout (floats): s[16384] | Wb (131072 f-slots) | part_e[262144] | part[524288]
    float* ws     = (float*)d_ws;
    float* s      = ws;
    uint4* Wb     = (uint4*)(ws + 16384);
    float* part_e = ws + 16384 + 131072;
    float* part   = part_e + 262144;

    hipLaunchKernelGGL(k_s,      dim3(64),      dim3(256),  0, stream, dec, Ws, s);
    hipLaunchKernelGGL(k_pack,   dim3(128),     dim3(256),  0, stream, Wh, Wb);
    hipLaunchKernelGGL(k_gemm_e, dim3(4096),    dim3(512),  0, stream, enc, Wb, s, v, part_e);
    hipLaunchKernelGGL(k_softmax,dim3(32),      dim3(1024), 0, stream, part_e, a, mask);
    hipLaunchKernelGGL(k_ctx,    dim3(32, 32),  dim3(256),  0, stream, enc, a, (float2*)part);
    hipLaunchKernelGGL(k_ctxred, dim3(64),      dim3(256),  0, stream, part, ctx);
}

// Round 9
// 186.349 us; speedup vs baseline: 1.1492x; 1.1492x over previous
//
#include <hip/hip_runtime.h>
#include <hip/hip_bf16.h>
#include <cstdint>
#include <cstddef>

#define HID 512
#define T_SZ 4096

typedef __bf16 bf16x8 __attribute__((ext_vector_type(8)));
typedef float f32x4 __attribute__((ext_vector_type(4)));

__device__ __forceinline__ unsigned short f2bf_rne(float f) {
    unsigned int u = __float_as_uint(f);
    unsigned int r = (u + 0x7FFFu + ((u >> 16) & 1u)) >> 16;
    return (unsigned short)r;
}

__device__ __forceinline__ float fast_tanh(float x) {
    float e = __expf(2.0f * x);
    return 1.0f - 2.0f / (e + 1.0f);
}

__device__ __forceinline__ void gload_lds16(const void* g, void* l) {
    __builtin_amdgcn_global_load_lds(
        (const __attribute__((address_space(1))) unsigned int*)g,
        (__attribute__((address_space(3))) unsigned int*)l, 16, 0, 0);
}

// ---------------- kernel 1: s[b][n] = dot(dec[b,:], Ws[n,:]) ----------------
__global__ void k_s(const float* __restrict__ dec, const float* __restrict__ Ws,
                    float* __restrict__ s) {
    int idx = blockIdx.x * 256 + threadIdx.x;   // 16384 = 32*512
    int b = idx >> 9, n = idx & 511;
    const float4* dp = reinterpret_cast<const float4*>(dec + (size_t)b * HID);
    const float4* wp = reinterpret_cast<const float4*>(Ws + (size_t)n * HID);
    float acc = 0.f;
#pragma unroll 8
    for (int i = 0; i < HID / 4; ++i) {
        float4 d = dp[i], w = wp[i];
        acc += d.x * w.x + d.y * w.y + d.z * w.z + d.w * w.w;
    }
    s[idx] = acc;
}

// ------------- kernel 2: pack W_h -> bf16 fragments (kk-major) --------------
// Chunk index = kk*2048 + n4*64 + (g*16 + c); chunk (uint4) holds
// W[n4*16 + c][kk*32 + g*8 + j], j=0..7 as bf16.
__global__ void k_pack(const float* __restrict__ Wh, uint4* __restrict__ Wb) {
    int idx = blockIdx.x * 256 + threadIdx.x;   // 32768, 8 elems each
    int n = idx >> 6;
    int k0 = (idx & 63) * 8;
    const float4* p = reinterpret_cast<const float4*>(Wh + (size_t)n * HID + k0);
    float4 x0 = p[0], x1 = p[1];
    uint4 w;
    w.x = f2bf_rne(x0.x) | ((unsigned)f2bf_rne(x0.y) << 16);
    w.y = f2bf_rne(x0.z) | ((unsigned)f2bf_rne(x0.w) << 16);
    w.z = f2bf_rne(x1.x) | ((unsigned)f2bf_rne(x1.y) << 16);
    w.w = f2bf_rne(x1.z) | ((unsigned)f2bf_rne(x1.w) << 16);
    int n4 = n >> 4, c = n & 15, kk = k0 >> 5, g = (k0 >> 3) & 3;
    Wb[(size_t)kk * 2048 + n4 * 64 + g * 16 + c] = w;
}

// ------------- kernel 3: fused h = enc@Wh^T ; e = sum_n tanh(h+s).v ---------
// BM=64, BN=512 (FULL N -> enc read once, no part_e), BK=32.
// 512 threads = 8 waves; wave owns 64 rows x 64 cols (acc 4x4 f32x4).
// B: per-step 32KB LDS double-buffer filled by global_load_lds from the
//    L2-resident packed Wb (B L2 traffic = 512KB/block, ~30x less than r8).
// A: reg-staged lead-2 (load kk-1 -> ds_write kk -> read kk+1), HBM covered.
// Barrier: counted "s_waitcnt vmcnt(1)" (B issued BEFORE A-load; in-order
// retirement => B done, newest HBM A-load stays in flight). Never vmcnt(0)
// mid-loop.
__global__ void __launch_bounds__(512, 2) k_gemm_e(
    const float* __restrict__ enc, const uint4* __restrict__ Wb,
    const float* __restrict__ s, const float* __restrict__ v,
    float* __restrict__ e_out) {
    __shared__ __align__(16) unsigned char Abuf[2][4096];    // 64r x 32k bf16
    __shared__ __align__(16) unsigned char Bbuf[2][32768];   // 2048 chunks 16B

    const int tid = threadIdx.x;
    const int lane = tid & 63, wid = tid >> 6;
    const int c16 = lane & 15, g4 = lane >> 4;
    const size_t row0 = (size_t)blockIdx.x * 64;
    const int b = (int)(row0 >> 12);

    // epilogue constants (wave's 4 n4-tiles)
    float sv_s[4], sv_v[4];
#pragma unroll
    for (int ni = 0; ni < 4; ++ni) {
        int n = (wid * 4 + ni) * 16 + c16;
        sv_s[ni] = s[b * HID + n];
        sv_v[ni] = v[n];
    }

    // ---- A staging geometry: thread owns 8B of each 4KB step-slice ----
    // chunk ac = tid>>1 (row=(ac>>6)*16+(ac&15), k8=(ac>>4)&3), half hh=tid&1
    const int ac = tid >> 1, hh = tid & 1;
    const int amrow = ((ac >> 6) << 4) + (ac & 15);
    const int ak = ((ac >> 4) & 3) * 8 + hh * 4;
    const float* Ag = enc + (row0 + amrow) * HID + ak;   // + kk*32 per step
    const int abyte = ac * 16 + hh * 8;

    // ---- B staging: wave-uniform LDS dest + per-lane global src ----
    const uint4* Bsrc = Wb + wid * 64 + lane;            // + kk*2048 + q*512

    // ================= prologue: B(0) -> Bbuf[0]; A(0) -> Abuf[0]; A(1)->regs
#pragma unroll
    for (int q = 0; q < 4; ++q)
        gload_lds16(Bsrc + q * 512, &Bbuf[0][(q * 512 + wid * 64) * 16]);
    float4 a0 = *reinterpret_cast<const float4*>(Ag);
    float4 aR[2];
    aR[1] = *reinterpret_cast<const float4*>(Ag + 32);
    {
        uint2 w;
        w.x = f2bf_rne(a0.x) | ((unsigned)f2bf_rne(a0.y) << 16);
        w.y = f2bf_rne(a0.z) | ((unsigned)f2bf_rne(a0.w) << 16);
        *reinterpret_cast<uint2*>(&Abuf[0][abyte]) = w;
    }
    // B(0)+A(0) retired (in-order); A(1) load stays in flight
    asm volatile("s_waitcnt vmcnt(1) lgkmcnt(0)\n\ts_barrier" ::: "memory");

    f32x4 acc[4][4] = {};   // [mi][ni]

#pragma unroll
    for (int kk = 0; kk < 16; ++kk) {
        // 1) ds_write A(kk+1) from regs loaded at kk-1 (full-step HBM cover)
        if (kk < 15) {
            float4 x = aR[(kk + 1) & 1];
            uint2 w;
            w.x = f2bf_rne(x.x) | ((unsigned)f2bf_rne(x.y) << 16);
            w.y = f2bf_rne(x.z) | ((unsigned)f2bf_rne(x.w) << 16);
            *reinterpret_cast<uint2*>(&Abuf[(kk + 1) & 1][abyte]) = w;
            // 2) stage B(kk+1) into Bbuf[(kk+1)&1] (L2-fast, done by barrier)
#pragma unroll
            for (int q = 0; q < 4; ++q)
                gload_lds16(Bsrc + (size_t)(kk + 1) * 2048 + q * 512,
                            &Bbuf[(kk + 1) & 1][(q * 512 + wid * 64) * 16]);
        }
        // 3) issue A(kk+2) global load LAST (newest -> excluded by vmcnt(1))
        if (kk < 14)
            aR[kk & 1] = *reinterpret_cast<const float4*>(Ag + (kk + 2) * 32);

        // 4) compute step kk
        bf16x8 af[4], bf[4];
#pragma unroll
        for (int mi = 0; mi < 4; ++mi)
            af[mi] = *reinterpret_cast<const bf16x8*>(
                &Abuf[kk & 1][(mi * 64 + lane) * 16]);
#pragma unroll
        for (int ni = 0; ni < 4; ++ni)
            bf[ni] = *reinterpret_cast<const bf16x8*>(
                &Bbuf[kk & 1][((wid * 4 + ni) * 64 + lane) * 16]);
#pragma unroll
        for (int mi = 0; mi < 4; ++mi)
#pragma unroll
            for (int ni = 0; ni < 4; ++ni)
                acc[mi][ni] = __builtin_amdgcn_mfma_f32_16x16x32_bf16(
                    af[mi], bf[ni], acc[mi][ni], 0, 0, 0);

        // 5) buffer handoff: counted vmcnt keeps the HBM A-load in flight
        if (kk < 14)
            asm volatile("s_waitcnt vmcnt(1) lgkmcnt(0)\n\ts_barrier" ::: "memory");
        else if (kk == 14)
            asm volatile("s_waitcnt vmcnt(0) lgkmcnt(0)\n\ts_barrier" ::: "memory");
    }

    // ---- epilogue: e[row] = sum_n tanh(h + s[n]) * v[n]  ----
    float e_part[4][4] = {};   // [mi][r]
#pragma unroll
    for (int ni = 0; ni < 4; ++ni) {
        float sn = sv_s[ni], vn = sv_v[ni];
#pragma unroll
        for (int mi = 0; mi < 4; ++mi)
#pragma unroll
            for (int r = 0; r < 4; ++r)
                e_part[mi][r] += fast_tanh(acc[mi][ni][r] + sn) * vn;
    }
    // reduce across the 16 n-residue lanes (bits 0..3)
#pragma unroll
    for (int mm = 1; mm <= 8; mm <<= 1)
#pragma unroll
        for (int mi = 0; mi < 4; ++mi)
#pragma unroll
            for (int r = 0; r < 4; ++r)
                e_part[mi][r] += __shfl_xor(e_part[mi][r], mm);

    __syncthreads();                       // all LDS reads done -> reuse Abuf
    float* red = reinterpret_cast<float*>(&Abuf[0][0]);   // [8][64]
    if (c16 == 0) {
#pragma unroll
        for (int mi = 0; mi < 4; ++mi)
#pragma unroll
            for (int r = 0; r < 4; ++r)
                red[wid * 64 + mi * 16 + g4 * 4 + r] = e_part[mi][r];
    }
    __syncthreads();
    if (tid < 64) {
        float sum = 0.f;
#pragma unroll
        for (int w = 0; w < 8; ++w) sum += red[w * 64 + tid];
        e_out[row0 + tid] = sum;
    }
}

// ---------------- kernel 4: masked softmax over T, in-place e->a ------------
__global__ void k_softmax(float* __restrict__ ea, const int* __restrict__ mask) {
    int b = blockIdx.x, tid = threadIdx.x;     // 1024 threads
    int lane = tid & 63, wid = tid >> 6;       // 16 waves
    __shared__ float red[16];
    float vals[4]; int ms[4];
    float mx = -1e30f;
#pragma unroll
    for (int j = 0; j < 4; ++j) {
        size_t t = (size_t)b * T_SZ + tid + j * 1024;
        vals[j] = ea[t];
        ms[j] = mask[t];
        if (ms[j]) mx = fmaxf(mx, vals[j]);
    }
#pragma unroll
    for (int m = 32; m >= 1; m >>= 1) mx = fmaxf(mx, __shfl_xor(mx, m));
    if (lane == 0) red[wid] = mx;
    __syncthreads();
    if (tid == 0) {
        float m2 = red[0];
        for (int i = 1; i < 16; ++i) m2 = fmaxf(m2, red[i]);
        red[0] = m2;
    }
    __syncthreads();
    mx = red[0];
    __syncthreads();
    float pv[4]; float sum = 0.f;
#pragma unroll
    for (int j = 0; j < 4; ++j) { pv[j] = ms[j] ? __expf(vals[j] - mx) : 0.f; sum += pv[j]; }
#pragma unroll
    for (int m = 32; m >= 1; m >>= 1) sum += __shfl_xor(sum, m);
    if (lane == 0) red[wid] = sum;
    __syncthreads();
    if (tid == 0) {
        float s2 = 0.f;
        for (int i = 0; i < 16; ++i) s2 += red[i];
        red[0] = s2;
    }
    __syncthreads();
    float inv = 1.f / red[0];
#pragma unroll
    for (int j = 0; j < 4; ++j) {
        size_t t = (size_t)b * T_SZ + tid + j * 1024;
        ea[t] = pv[j] * inv;
    }
}

// ---------------- kernel 5: ctx partials over T-chunks ----------------------
__global__ void k_ctx(const float* __restrict__ enc, const float* __restrict__ a,
                      float2* __restrict__ part) {
    int ts = blockIdx.x, b = blockIdx.y, tid = threadIdx.x;   // 32 x 32, 256 thr
    size_t rbase = (size_t)b * T_SZ + (size_t)ts * 128;
    const float2* ep = reinterpret_cast<const float2*>(enc + rbase * HID) + tid;
    const float* ap = a + rbase;
    float ax = 0.f, ay = 0.f, bx = 0.f, by = 0.f;
#pragma unroll 2
    for (int t = 0; t < 128; t += 2) {
        float a0 = ap[t], a1 = ap[t + 1];
        float2 e0 = ep[(size_t)t * 256], e1 = ep[(size_t)(t + 1) * 256];
        ax += a0 * e0.x; ay += a0 * e0.y;
        bx += a1 * e1.x; by += a1 * e1.y;
    }
    float2 r; r.x = ax + bx; r.y = ay + by;
    part[(size_t)(b * 32 + ts) * 256 + tid] = r;
}

// ---------------- kernel 6: reduce partials -> ctx --------------------------
__global__ void k_ctxred(const float* __restrict__ part, float* __restrict__ ctx) {
    int idx = blockIdx.x * 256 + threadIdx.x;   // 16384
    int b = idx >> 9, h = idx & 511;
    float sum = 0.f;
#pragma unroll
    for (int ts = 0; ts < 32; ++ts) sum += part[(size_t)(b * 32 + ts) * 512 + h];
    ctx[idx] = sum;
}

extern "C" void kernel_launch(void* const* d_in, const int* in_sizes, int n_in,
                              void* d_out, int out_size, void* d_ws, size_t ws_size,
                              hipStream_t stream) {
    const float* enc  = (const float*)d_in[0];   // [32,4096,512]
    const int*   mask = (const int*)d_in[1];     // [32,4096]
    const float* dec  = (const float*)d_in[2];   // [32,512]
    const float* Wh   = (const float*)d_in[3];   // [512,512]
    const float* Ws   = (const float*)d_in[4];   // [512,512]
    const float* v    = (const float*)d_in[5];   // [512]

    float* out = (float*)d_out;
    float* ctx = out;                // 16384 floats
    float* a   = out + 16384;        // 131072 floats (e then a, in place)

    // ws layout (floats): s[16384] | Wb (131072 f-slots) | part[524288]
    float* ws   = (float*)d_ws;
    float* s    = ws;
    uint4* Wb   = (uint4*)(ws + 16384);
    float* part = ws + 16384 + 131072;

    hipLaunchKernelGGL(k_s,      dim3(64),      dim3(256),  0, stream, dec, Ws, s);
    hipLaunchKernelGGL(k_pack,   dim3(128),     dim3(256),  0, stream, Wh, Wb);
    hipLaunchKernelGGL(k_gemm_e, dim3(2048),    dim3(512),  0, stream, enc, Wb, s, v, a);
    hipLaunchKernelGGL(k_softmax,dim3(32),      dim3(1024), 0, stream, a, mask);
    hipLaunchKernelGGL(k_ctx,    dim3(32, 32),  dim3(256),  0, stream, enc, a, (float2*)part);
    hipLaunchKernelGGL(k_ctxred, dim3(64),      dim3(256),  0, stream, part, ctx);
}